// Round 1
// baseline (2092.839 us; speedup 1.0000x reference)
//
#include <hip/hip_runtime.h>

#define MUL 64
#define N_NODES 10000
#define N_EDGES 320000
#define DIM 256

static constexpr float SQ3     = 1.7320508075688772f;
static constexpr float INV_SQ3 = 0.5773502691896258f;
static constexpr float INV_MUL = 0.125f;               // 1/sqrt(64)
static constexpr float INV_TP  = 0.08838834764831845f; // 1/sqrt(128)

__device__ __forceinline__ float bcast(float v, int lane) {
    return __builtin_bit_cast(float, __builtin_amdgcn_readlane(__builtin_bit_cast(int, v), lane));
}

// y[e] += sum_u x[e][u_broadcast] * W[u][lane]
template<int E>
__device__ __forceinline__ void matvec_acc(const float* __restrict__ W, int lane,
                                           const float (&x)[E], float (&y)[E]) {
#pragma unroll 16
    for (int u = 0; u < 64; ++u) {
        float w = W[u * 64 + lane];
#pragma unroll
        for (int e = 0; e < E; ++e)
            y[e] = fmaf(bcast(x[e], u), w, y[e]);
    }
}

__device__ __forceinline__ float wave_max(float v) {
#pragma unroll
    for (int m = 32; m >= 1; m >>= 1) v = fmaxf(v, __shfl_xor(v, m, 64));
    return v;
}
__device__ __forceinline__ float wave_sum(float v) {
#pragma unroll
    for (int m = 32; m >= 1; m >>= 1) v += __shfl_xor(v, m, 64);
    return v;
}

__global__ __launch_bounds__(256) void init_out_kernel(const float* __restrict__ af,
                                                       float* __restrict__ out) {
    int i = blockIdx.x * blockDim.x + threadIdx.x;   // over float4 elements
    reinterpret_cast<float4*>(out)[i] = reinterpret_cast<const float4*>(af)[i];
}

template<int E>
__global__ __launch_bounds__(256) void edge_kernel(
    const float* __restrict__ af, const float* __restrict__ ev,
    const int* __restrict__ ei,
    const float* __restrict__ ls0, const float* __restrict__ ls1,
    const float* __restrict__ t100, const float* __restrict__ t111,
    const float* __restrict__ t101, const float* __restrict__ t110,
    const float* __restrict__ t200, const float* __restrict__ t211,
    const float* __restrict__ t201, const float* __restrict__ t210,
    const float* __restrict__ lh0, const float* __restrict__ lh1,
    const float* __restrict__ lsc,
    float* __restrict__ out)
{
    const int lane = threadIdx.x & 63;
    const int wave = threadIdx.x >> 6;
    const int wid  = blockIdx.x * 4 + wave;
    const int e0   = wid * E;

    int   dst[E];
    float sh[3][E];
    float x0[E], x1[3][E];

#pragma unroll
    for (int e = 0; e < E; ++e) {
        const int eid = e0 + e;
        const int s  = ei[eid];
        dst[e]       = ei[N_EDGES + eid];
        const float vx = ev[3 * eid + 0];
        const float vy = ev[3 * eid + 1];
        const float vz = ev[3 * eid + 2];
        const float inv = 1.0f / (sqrtf(vx * vx + vy * vy + vz * vz) + 1e-12f);
        sh[0][e] = SQ3 * vx * inv;
        sh[1][e] = SQ3 * vy * inv;
        sh[2][e] = SQ3 * vz * inv;
        const float* __restrict__ row = af + (size_t)s * DIM;
        x0[e]    = row[lane];
        x1[0][e] = row[64 + 3 * lane + 0];
        x1[1][e] = row[64 + 3 * lane + 1];
        x1[2][e] = row[64 + 3 * lane + 2];
    }

    // ---- lin_src ----
    float s0[E] = {0.f, 0.f, 0.f, 0.f};
    matvec_acc<E>(ls0, lane, x0, s0);
    float s1[3][E];
#pragma unroll
    for (int m = 0; m < 3; ++m) {
#pragma unroll
        for (int e = 0; e < E; ++e) s1[m][e] = 0.f;
        matvec_acc<E>(ls1, lane, x1[m], s1[m]);
    }
#pragma unroll
    for (int e = 0; e < E; ++e) {
        s0[e] *= INV_MUL;
#pragma unroll
        for (int m = 0; m < 3; ++m) s1[m][e] *= INV_MUL;
    }

    // ---- fctp1 ----
    float dot[E];
#pragma unroll
    for (int e = 0; e < E; ++e)
        dot[e] = (s1[0][e] * sh[0][e] + s1[1][e] * sh[1][e] + s1[2][e] * sh[2][e]) * INV_SQ3;

    float h0[E] = {0.f, 0.f, 0.f, 0.f};
    matvec_acc<E>(t100, lane, s0, h0);
    matvec_acc<E>(t111, lane, dot, h0);
    float p01[E] = {0.f, 0.f, 0.f, 0.f};
    matvec_acc<E>(t101, lane, s0, p01);
    float h1[3][E];
#pragma unroll
    for (int m = 0; m < 3; ++m) {
#pragma unroll
        for (int e = 0; e < E; ++e) h1[m][e] = 0.f;
        matvec_acc<E>(t110, lane, s1[m], h1[m]);
#pragma unroll
        for (int e = 0; e < E; ++e)
            h1[m][e] = (p01[e] * sh[m][e] + h1[m][e]) * INV_TP;
    }
#pragma unroll
    for (int e = 0; e < E; ++e) h0[e] *= INV_TP;

    // ---- lin_hidden ----
    float g0[E] = {0.f, 0.f, 0.f, 0.f};
    matvec_acc<E>(lh0, lane, h0, g0);
    float g1[3][E];
#pragma unroll
    for (int m = 0; m < 3; ++m) {
#pragma unroll
        for (int e = 0; e < E; ++e) g1[m][e] = 0.f;
        matvec_acc<E>(lh1, lane, h1[m], g1[m]);
#pragma unroll
        for (int e = 0; e < E; ++e) g1[m][e] *= INV_MUL;
    }
#pragma unroll
    for (int e = 0; e < E; ++e) g0[e] *= INV_MUL;

    // ---- lin_scalar + softmax ----
    float lr[E];
#pragma unroll
    for (int e = 0; e < E; ++e) lr[e] = g0[e] > 0.f ? g0[e] : 0.01f * g0[e];
    float sc[E] = {0.f, 0.f, 0.f, 0.f};
    matvec_acc<E>(lsc, lane, lr, sc);

    float act0[E], act1[E];
#pragma unroll
    for (int e = 0; e < E; ++e) {
        const float scv = sc[e] * INV_MUL;
        float mx = wave_max(scv);
        mx = fmaxf(mx, 0.f);                    // 192 zero entries participate
        const float pe = __expf(scv - mx);
        const float S  = wave_sum(pe);
        const float ez = __expf(-mx);
        const float Z  = S + 192.f * ez;
        const float invZ = 1.0f / Z;
        act0[e] = pe * invZ;
        act1[e] = ez * invZ;
    }

    // ---- fctp2 ----
    float dot2[E];
#pragma unroll
    for (int e = 0; e < E; ++e)
        dot2[e] = (g1[0][e] * sh[0][e] + g1[1][e] * sh[1][e] + g1[2][e] * sh[2][e]) * INV_SQ3;

    float o0[E] = {0.f, 0.f, 0.f, 0.f};
    matvec_acc<E>(t200, lane, g0, o0);
    matvec_acc<E>(t211, lane, dot2, o0);
    float q[E] = {0.f, 0.f, 0.f, 0.f};
    matvec_acc<E>(t201, lane, g0, q);
    float o1[3][E];
#pragma unroll
    for (int m = 0; m < 3; ++m) {
#pragma unroll
        for (int e = 0; e < E; ++e) o1[m][e] = 0.f;
        matvec_acc<E>(t210, lane, g1[m], o1[m]);
#pragma unroll
        for (int e = 0; e < E; ++e)
            o1[m][e] = (q[e] * sh[m][e] + o1[m][e]) * INV_TP;
    }

    // ---- scatter (atomic segment-sum) ----
#pragma unroll
    for (int e = 0; e < E; ++e) {
        float* __restrict__ orow = out + (size_t)dst[e] * DIM;
        atomicAdd(orow + lane, act0[e] * o0[e] * INV_TP);
#pragma unroll
        for (int m = 0; m < 3; ++m)
            atomicAdd(orow + 64 + 3 * lane + m, act1[e] * o1[m][e]);
    }
}

extern "C" void kernel_launch(void* const* d_in, const int* in_sizes, int n_in,
                              void* d_out, int out_size, void* d_ws, size_t ws_size,
                              hipStream_t stream) {
    const float* ls0  = (const float*)d_in[0];
    const float* ls1  = (const float*)d_in[1];
    // d_in[2], d_in[3] = lin_dst_w0/w1 — dead code in the reference forward
    const float* t100 = (const float*)d_in[4];
    const float* t111 = (const float*)d_in[5];
    const float* t101 = (const float*)d_in[6];
    const float* t110 = (const float*)d_in[7];
    const float* t200 = (const float*)d_in[8];
    const float* t211 = (const float*)d_in[9];
    const float* t201 = (const float*)d_in[10];
    const float* t210 = (const float*)d_in[11];
    const float* lh0  = (const float*)d_in[12];
    const float* lh1  = (const float*)d_in[13];
    const float* lsc  = (const float*)d_in[14];
    const float* af   = (const float*)d_in[15];
    const float* ev   = (const float*)d_in[16];
    const int*   ei   = (const int*)d_in[17];
    float* out = (float*)d_out;

    // residual init: out = atom_feature  (10000*256 floats = 640000 float4)
    hipLaunchKernelGGL(init_out_kernel, dim3(N_NODES * DIM / 4 / 256), dim3(256), 0, stream,
                       af, out);

    // 320000 edges / (4 edges/wave * 4 waves/block) = 20000 blocks
    hipLaunchKernelGGL((edge_kernel<4>), dim3(N_EDGES / 16), dim3(256), 0, stream,
                       af, ev, ei,
                       ls0, ls1, t100, t111, t101, t110,
                       t200, t211, t201, t210, lh0, lh1, lsc,
                       out);
}

// Round 3
// 785.309 us; speedup vs baseline: 2.6650x; 2.6650x over previous
//
#include <hip/hip_runtime.h>

#define N_NODES 10000
#define N_EDGES 320000
#define DIM 256

typedef __attribute__((ext_vector_type(8))) short bf16x8;
typedef __attribute__((ext_vector_type(4))) float f32x4;

static constexpr float SQ3     = 1.7320508075688772f;
static constexpr float INV_SQ3 = 0.5773502691896258f;
static constexpr float INV_MUL = 0.125f;               // 1/sqrt(64)
static constexpr float INV_TP  = 0.08838834764831845f; // 1/sqrt(128)

__device__ __forceinline__ unsigned short f2bf(float f) {
    unsigned b = __builtin_bit_cast(unsigned, f);
    b += 0x7FFFu + ((b >> 16) & 1u);            // RNE
    return (unsigned short)(b >> 16);
}
__device__ __forceinline__ float bf2f(unsigned short h) {
    return __builtin_bit_cast(float, ((unsigned)h) << 16);
}

__device__ __forceinline__ f32x4 MFMA(bf16x8 a, bf16x8 b, f32x4 c) {
    return __builtin_amdgcn_mfma_f32_16x16x32_bf16(a, b, c, 0, 0, 0);
}

// A-fragment pair (hi/lo split) covering K=64 in 2 ksteps of 32
struct AF { bf16x8 hi[2], lo[2]; };

__device__ __forceinline__ void split8(const float* v, bf16x8& hi, bf16x8& lo) {
#pragma unroll
    for (int j = 0; j < 8; ++j) {
        unsigned short h = f2bf(v[j]);
        hi[j] = (short)h;
        lo[j] = (short)f2bf(v[j] - bf2f(h));
    }
}

__device__ __forceinline__ void zacc(f32x4* a) {
#pragma unroll
    for (int i = 0; i < 4; ++i) a[i] = (f32x4){0.f, 0.f, 0.f, 0.f};
}

// y[16e x 64v] += x[16e x 64u] * W[64u x 64v], 3-term split precision.
// wm: packed frags [hl][ks][nt][lane][8] (ushorts), hl-plane stride 4096.
__device__ __forceinline__ void mv_acc(const AF& a, const unsigned short* __restrict__ wm,
                                       f32x4* acc) {
    const int l = threadIdx.x & 63;
#pragma unroll
    for (int ks = 0; ks < 2; ++ks) {
#pragma unroll
        for (int nt = 0; nt < 4; ++nt) {
            bf16x8 bh = *(const bf16x8*)(wm + (ks * 4 + nt) * 512 + l * 8);
            bf16x8 bl = *(const bf16x8*)(wm + 4096 + (ks * 4 + nt) * 512 + l * 8);
            acc[nt] = MFMA(a.hi[ks], bh, acc[nt]);
            acc[nt] = MFMA(a.lo[ks], bh, acc[nt]);
            acc[nt] = MFMA(a.hi[ks], bl, acc[nt]);
        }
    }
}

// LDS tile: [16 rows][68 floats] (pad 4 breaks bank-conflict power-of-2 stride)
__device__ __forceinline__ void store_D(float* __restrict__ buf, const f32x4* acc, float scale) {
    const int l = threadIdx.x & 63;
    const int c = l & 15, rgp = l >> 4;
#pragma unroll
    for (int nt = 0; nt < 4; ++nt)
#pragma unroll
        for (int r = 0; r < 4; ++r)
            buf[(rgp * 4 + r) * 68 + nt * 16 + c] = acc[nt][r] * scale;
}

__device__ __forceinline__ void store_D_h1(float* __restrict__ buf, const f32x4* p01,
                                           const float shDm[4], const f32x4* acc) {
    const int l = threadIdx.x & 63;
    const int c = l & 15, rgp = l >> 4;
#pragma unroll
    for (int nt = 0; nt < 4; ++nt)
#pragma unroll
        for (int r = 0; r < 4; ++r)
            buf[(rgp * 4 + r) * 68 + nt * 16 + c] =
                (p01[nt][r] * shDm[r] + acc[nt][r]) * INV_TP;
}

__device__ __forceinline__ void read_row8(const float* __restrict__ buf, int ks, float* v) {
    const int l = threadIdx.x & 63;
    const float* p = buf + (l & 15) * 68 + (l >> 4) * 8 + ks * 32;
    f32x4 x = *(const f32x4*)(p);
    f32x4 y = *(const f32x4*)(p + 4);
    v[0] = x[0]; v[1] = x[1]; v[2] = x[2]; v[3] = x[3];
    v[4] = y[0]; v[5] = y[1]; v[6] = y[2]; v[7] = y[3];
}

__device__ __forceinline__ void build_A(const float* __restrict__ buf, AF& a) {
#pragma unroll
    for (int ks = 0; ks < 2; ++ks) {
        float v[8];
        read_row8(buf, ks, v);
        split8(v, a.hi[ks], a.lo[ks]);
    }
}

// build A-frag and accumulate dot: dv[ks][j] += v[j] * shm  (lane's row is fixed)
__device__ __forceinline__ void build_A_dot(const float* __restrict__ buf, AF& a, float shm,
                                            float dv[2][8]) {
#pragma unroll
    for (int ks = 0; ks < 2; ++ks) {
        float v[8];
        read_row8(buf, ks, v);
#pragma unroll
        for (int j = 0; j < 8; ++j) dv[ks][j] = fmaf(v[j], shm, dv[ks][j]);
        split8(v, a.hi[ks], a.lo[ks]);
    }
}

__device__ __forceinline__ void build_A_leaky(const float* __restrict__ buf, AF& a, AF& alr) {
#pragma unroll
    for (int ks = 0; ks < 2; ++ks) {
        float v[8];
        read_row8(buf, ks, v);
        split8(v, a.hi[ks], a.lo[ks]);
        float w[8];
#pragma unroll
        for (int j = 0; j < 8; ++j) w[j] = v[j] > 0.f ? v[j] : 0.01f * v[j];
        split8(w, alr.hi[ks], alr.lo[ks]);
    }
}

__global__ __launch_bounds__(256) void init_out_kernel(const float* __restrict__ af,
                                                       float* __restrict__ out) {
    int i = blockIdx.x * blockDim.x + threadIdx.x;
    reinterpret_cast<float4*>(out)[i] = reinterpret_cast<const float4*>(af)[i];
}

// Pre-pack 13 weight mats into MFMA B-frag layout, hi/lo bf16.
// Per mat: [hl(2)][ks(2)][nt(4)][lane(64)][j(8)] ushorts = 8192; total 13*16KB.
__global__ __launch_bounds__(256) void prep_w(
    const float* a0, const float* a1, const float* a2, const float* a3,
    const float* a4, const float* a5, const float* a6, const float* a7,
    const float* a8, const float* a9, const float* a10, const float* a11,
    const float* a12, unsigned short* __restrict__ o)
{
    const float* mats[13] = {a0,a1,a2,a3,a4,a5,a6,a7,a8,a9,a10,a11,a12};
    const float* W = mats[blockIdx.x];
    unsigned short* dst = o + blockIdx.x * 8192;
    for (int t = threadIdx.x; t < 4096; t += 256) {
        int u = t >> 6, v = t & 63;          // W[u][v]
        float val = W[t];
        unsigned short hi = f2bf(val);
        unsigned short lo = f2bf(val - bf2f(hi));
        int ks = u >> 5, g = (u >> 3) & 3, j = u & 7;
        int base = ((ks * 4 + (v >> 4)) * 64 + ((v & 15) + 16 * g)) * 8 + j;
        dst[base] = hi;
        dst[4096 + base] = lo;
    }
}

__global__ __launch_bounds__(256, 2) void edge_kernel(
    const float* __restrict__ af, const float* __restrict__ ev,
    const int* __restrict__ ei, const unsigned short* __restrict__ wb,
    float* __restrict__ out)
{
    __shared__ float lds[4][4][16 * 68];      // [wave][buf][16x68] = 69632 B
    const int l  = threadIdx.x & 63;
    const int wv = threadIdx.x >> 6;
    const int rg = l >> 4;
    const int e0 = (blockIdx.x * 4 + wv) * 16;
    float* B0 = lds[wv][0];
    float* B1 = lds[wv][1];
    float* B2 = lds[wv][2];
    float* B3 = lds[wv][3];
    float* Bm[3] = {B1, B2, B3};

    // ---- per-edge metadata (no LDS; redundant loads hit L1) ----
    float shA[3];                              // sh[m][row = l&15]  (A-side row fixed per lane)
    {
        int e = e0 + (l & 15);
        float x = ev[3*e], y = ev[3*e+1], z = ev[3*e+2];
        float s = SQ3 / (sqrtf(x*x + y*y + z*z) + 1e-12f);
        shA[0] = x*s; shA[1] = y*s; shA[2] = z*s;
    }
    float shD[4][3]; int dstD[4];              // D-side rows rg*4+r
#pragma unroll
    for (int r = 0; r < 4; ++r) {
        int e = e0 + rg * 4 + r;
        float x = ev[3*e], y = ev[3*e+1], z = ev[3*e+2];
        float s = SQ3 / (sqrtf(x*x + y*y + z*z) + 1e-12f);
        shD[r][0] = x*s; shD[r][1] = y*s; shD[r][2] = z*s;
        dstD[r] = ei[N_EDGES + e];
    }

    // ---- stage-1 A-frags straight from global (af row of this lane's edge) ----
    AF x0a, x1a[3];
    {
        const int node = ei[e0 + (l & 15)];
        const float* rp = af + (long)node * DIM;
#pragma unroll
        for (int ks = 0; ks < 2; ++ks) {
            const int u0 = rg * 8 + ks * 32;
            f32x4 xa = *(const f32x4*)(rp + u0);
            f32x4 xb = *(const f32x4*)(rp + u0 + 4);
            float v[8] = {xa[0],xa[1],xa[2],xa[3],xb[0],xb[1],xb[2],xb[3]};
            split8(v, x0a.hi[ks], x0a.lo[ks]);
            f32x4 sp[6];
#pragma unroll
            for (int q = 0; q < 6; ++q) sp[q] = *(const f32x4*)(rp + 64 + 3 * u0 + 4 * q);
#pragma unroll
            for (int m = 0; m < 3; ++m) {
                float w[8];
#pragma unroll
                for (int j = 0; j < 8; ++j) { int idx = 3 * j + m; w[j] = sp[idx >> 2][idx & 3]; }
                split8(w, x1a[m].hi[ks], x1a[m].lo[ks]);
            }
        }
    }

    f32x4 acc[4];

    // ---- lin_src: s1m -> B1..B3, s0 -> B0 ----
#pragma unroll
    for (int m = 0; m < 3; ++m) {
        zacc(acc); mv_acc(x1a[m], wb + 1 * 8192, acc);
        store_D(Bm[m], acc, INV_MUL);
    }
    zacc(acc); mv_acc(x0a, wb + 0 * 8192, acc);
    store_D(B0, acc, INV_MUL);
    asm volatile("s_waitcnt lgkmcnt(0)" ::: "memory");

    // ---- build s A-frags (+dot fused) ----
    AF s0a, s1a[3], dota;
    build_A(B0, s0a);
    {
        float dv[2][8] = {};
#pragma unroll
        for (int m = 0; m < 3; ++m) build_A_dot(Bm[m], s1a[m], shA[m], dv);
        float d0[8], d1[8];
#pragma unroll
        for (int j = 0; j < 8; ++j) { d0[j] = dv[0][j] * INV_SQ3; d1[j] = dv[1][j] * INV_SQ3; }
        split8(d0, dota.hi[0], dota.lo[0]);
        split8(d1, dota.hi[1], dota.lo[1]);
    }

    // ---- fctp1: h0 -> B0, h1m -> B1..B3 ----
    zacc(acc); mv_acc(s0a, wb + 2 * 8192, acc); mv_acc(dota, wb + 3 * 8192, acc);
    store_D(B0, acc, INV_TP);                      // h0 (s0a already in regs)
    f32x4 p01[4];
    zacc(p01); mv_acc(s0a, wb + 4 * 8192, p01);
#pragma unroll
    for (int m = 0; m < 3; ++m) {
        zacc(acc); mv_acc(s1a[m], wb + 5 * 8192, acc);
        float shm[4] = {shD[0][m], shD[1][m], shD[2][m], shD[3][m]};
        store_D_h1(Bm[m], p01, shm, acc);          // (p01*sh + s1*t110)*INV_TP
    }
    asm volatile("s_waitcnt lgkmcnt(0)" ::: "memory");

    // ---- lin_hidden: g0 -> B0, g1m -> B1..B3 ----
    AF h0a, h1a[3];
    build_A(B0, h0a);
#pragma unroll
    for (int m = 0; m < 3; ++m) build_A(Bm[m], h1a[m]);
    zacc(acc); mv_acc(h0a, wb + 6 * 8192, acc);
    store_D(B0, acc, INV_MUL);                     // g0
#pragma unroll
    for (int m = 0; m < 3; ++m) {
        zacc(acc); mv_acc(h1a[m], wb + 7 * 8192, acc);
        store_D(Bm[m], acc, INV_MUL);              // g1m
    }
    asm volatile("s_waitcnt lgkmcnt(0)" ::: "memory");

    // ---- build g A-frags (+lr, +dot2 fused; no extra LDS buffers) ----
    AF g0a, lra, g1a[3], dot2a;
    build_A_leaky(B0, g0a, lra);
    {
        float dv[2][8] = {};
#pragma unroll
        for (int m = 0; m < 3; ++m) build_A_dot(Bm[m], g1a[m], shA[m], dv);
        float d0[8], d1[8];
#pragma unroll
        for (int j = 0; j < 8; ++j) { d0[j] = dv[0][j] * INV_SQ3; d1[j] = dv[1][j] * INV_SQ3; }
        split8(d0, dot2a.hi[0], dot2a.lo[0]);
        split8(d1, dot2a.hi[1], dot2a.lo[1]);
    }

    // ---- lin_scalar + softmax (64 reals + 192 zeros) ----
    f32x4 sc[4];
    zacc(sc); mv_acc(lra, wb + 8 * 8192, sc);
    float act1r[4];
    {
#pragma unroll
        for (int nt = 0; nt < 4; ++nt) sc[nt] *= INV_MUL;
#pragma unroll
        for (int r = 0; r < 4; ++r) {
            float mx = fmaxf(fmaxf(sc[0][r], sc[1][r]), fmaxf(sc[2][r], sc[3][r]));
#pragma unroll
            for (int w = 1; w <= 8; w <<= 1) mx = fmaxf(mx, __shfl_xor(mx, w, 64));
            mx = fmaxf(mx, 0.f);
            float s_ = 0.f;
#pragma unroll
            for (int nt = 0; nt < 4; ++nt) { float p = __expf(sc[nt][r] - mx); sc[nt][r] = p; s_ += p; }
#pragma unroll
            for (int w = 1; w <= 8; w <<= 1) s_ += __shfl_xor(s_, w, 64);
            float ez = __expf(-mx);
            float invZ = 1.0f / (s_ + 192.f * ez);
#pragma unroll
            for (int nt = 0; nt < 4; ++nt) sc[nt][r] *= invZ;   // act0
            act1r[r] = ez * invZ;                                // act for 192 vector chans
        }
    }

    // ---- fctp2 + scatter ----
    f32x4 o0[4];
    zacc(o0); mv_acc(g0a, wb + 9 * 8192, o0); mv_acc(dot2a, wb + 10 * 8192, o0);
    f32x4 qD[4];
    zacc(qD); mv_acc(g0a, wb + 11 * 8192, qD);

#pragma unroll
    for (int nt = 0; nt < 4; ++nt)
#pragma unroll
        for (int r = 0; r < 4; ++r)
            atomicAdd(out + (long)dstD[r] * DIM + nt * 16 + (l & 15),
                      sc[nt][r] * o0[nt][r] * INV_TP);

#pragma unroll
    for (int m = 0; m < 3; ++m) {
        zacc(acc); mv_acc(g1a[m], wb + 12 * 8192, acc);
#pragma unroll
        for (int nt = 0; nt < 4; ++nt)
#pragma unroll
            for (int r = 0; r < 4; ++r) {
                float val = (qD[nt][r] * shD[r][m] + acc[nt][r]) * INV_TP * act1r[r];
                atomicAdd(out + (long)dstD[r] * DIM + 64 + 3 * (nt * 16 + (l & 15)) + m, val);
            }
    }
}

extern "C" void kernel_launch(void* const* d_in, const int* in_sizes, int n_in,
                              void* d_out, int out_size, void* d_ws, size_t ws_size,
                              hipStream_t stream) {
    const float* ls0  = (const float*)d_in[0];
    const float* ls1  = (const float*)d_in[1];
    // d_in[2], d_in[3] = lin_dst (dead code in reference forward)
    const float* t100 = (const float*)d_in[4];
    const float* t111 = (const float*)d_in[5];
    const float* t101 = (const float*)d_in[6];
    const float* t110 = (const float*)d_in[7];
    const float* t200 = (const float*)d_in[8];
    const float* t211 = (const float*)d_in[9];
    const float* t201 = (const float*)d_in[10];
    const float* t210 = (const float*)d_in[11];
    const float* lh0  = (const float*)d_in[12];
    const float* lh1  = (const float*)d_in[13];
    const float* lsc  = (const float*)d_in[14];
    const float* af   = (const float*)d_in[15];
    const float* ev   = (const float*)d_in[16];
    const int*   ei   = (const int*)d_in[17];
    float* out = (float*)d_out;
    unsigned short* wbuf = (unsigned short*)d_ws;   // 13*8192 ushorts = 208 KB

    // pack weights into MFMA B-frag hi/lo layout (runs every launch; d_ws is re-poisoned)
    hipLaunchKernelGGL(prep_w, dim3(13), dim3(256), 0, stream,
                       ls0, ls1, t100, t111, t101, t110, lh0, lh1, lsc,
                       t200, t211, t201, t210, wbuf);

    // residual init: out = atom_feature
    hipLaunchKernelGGL(init_out_kernel, dim3(N_NODES * DIM / 4 / 256), dim3(256), 0, stream,
                       af, out);

    // 320000 edges / (16 per wave * 4 waves) = 5000 blocks
    hipLaunchKernelGGL(edge_kernel, dim3(N_EDGES / 64), dim3(256), 0, stream,
                       af, ev, ei, wbuf, out);
}